// Round 7
// baseline (6639.925 us; speedup 1.0000x reference)
//
#include <hip/hip_runtime.h>
#include <stdint.h>

// Problem: B=64, DIM=512, T=2048, S=1024.
// out[b][s][t] = softmax_s( 2*cross - msq[s] ),  cross = sum_d units[d][s]*H[b][d][t].
// Pipeline:
//   k_prep_units: units fp32 -> Upack hi/lo (MFMA-fragment-slab order) + msq[s].
//   k_prep_h:     H fp32 -> Bpack hi/lo (fragment-slab order per (b, t-group-64)).
//   k_fused:      FULL-S GEMM (1024s x 128t per block) 32x32x16 MFMA, 3-term hi/lo.
//                 NO LDS / NO barriers in K-loop: operands are pre-packed in fragment
//                 order, so A and B fragments load straight global->VGPR (coalesced
//                 1KB wave-loads; U is L2-resident, B wave-duplicates hit L1).
//                 Register double-buffer (2 static sets), compiler-managed vmcnt.
//                 In-register softmax epilogue (LDS only for 8KB reductions).
// ws: BpackH[0,128M) BpackL[128M,256M) UpackH(1M) UpackL(1M) msq(4K) => ~258 MB.

typedef unsigned short u16;
typedef __attribute__((ext_vector_type(8))) short short8;    // 8 x bf16 (4 VGPR)
typedef __attribute__((ext_vector_type(4))) float f32x4;
typedef __attribute__((ext_vector_type(16))) float f32x16;   // 32x32 C/D

#define B_DIM 64
#define DIM   512
#define T_DIM 2048
#define S_DIM 1024

__device__ __forceinline__ u16 f32_to_bf16(float f) {
  uint32_t u = __float_as_uint(f);
  uint32_t r = u + 0x7FFFu + ((u >> 16) & 1u);   // RNE
  return (u16)(r >> 16);
}
__device__ __forceinline__ float bf16_to_f32(u16 h) {
  return __uint_as_float(((uint32_t)h) << 16);
}

// Fragment-chunk math (R5/R6-verified):
//   A slab ks (16 d), tile ts (32 s): byte = ks*32768 + ts*1024 + (khalf*32 + s31)*16 + e*2,
//     lane l = lhi*32+l31 reads chunk (lhi,l31) -> addr = base + ts*1024 + lane*16.
//   B per (b, tgroup64): byte = group*65536... (slab stride 2048) + nt64*1024 + lane*16.

// ---------------- K0a: units -> Upack hi/lo + msq ----------------
__global__ __launch_bounds__(256) void k_prep_units(const float* __restrict__ units,
                                                    u16* __restrict__ UpH, u16* __restrict__ UpL,
                                                    float* __restrict__ msq) {
  const int s0 = blockIdx.x * 4;
  const int tid = threadIdx.x;
  const int lane = tid & 63, wv = tid >> 6;
  float acc0 = 0.f, acc1 = 0.f, acc2 = 0.f, acc3 = 0.f;
#pragma unroll
  for (int j = 0; j < 2; ++j) {
    const int d = tid + j * 256;
    const float4 v = *(const float4*)(units + (size_t)d * S_DIM + s0);
    acc0 += v.x * v.x; acc1 += v.y * v.y; acc2 += v.z * v.z; acc3 += v.w * v.w;
    const int dbase = (d >> 4) * 16384 + ((d >> 3) & 1) * 256 + (d & 7);
    const float fv[4] = {v.x, v.y, v.z, v.w};
#pragma unroll
    for (int q = 0; q < 4; ++q) {
      const int s = s0 + q;
      const int idx = dbase + ((s >> 5) * 64 + (s & 31)) * 8;
      const u16 h = f32_to_bf16(fv[q]);
      UpH[idx] = h;
      UpL[idx] = f32_to_bf16(fv[q] - bf16_to_f32(h));
    }
  }
#pragma unroll
  for (int off = 1; off < 64; off <<= 1) {
    acc0 += __shfl_xor(acc0, off);
    acc1 += __shfl_xor(acc1, off);
    acc2 += __shfl_xor(acc2, off);
    acc3 += __shfl_xor(acc3, off);
  }
  __shared__ float part[4][4];
  if (lane == 0) { part[wv][0] = acc0; part[wv][1] = acc1; part[wv][2] = acc2; part[wv][3] = acc3; }
  __syncthreads();
  if (tid < 4) msq[s0 + tid] = part[0][tid] + part[1][tid] + part[2][tid] + part[3][tid];
}

// ---------------- K0b: H [b][d][t] -> Bpack hi/lo ----------------
__global__ __launch_bounds__(256) void k_prep_h(const float* __restrict__ H,
                                                u16* __restrict__ BpH, u16* __restrict__ BpL) {
  __shared__ float tile[64 * 68];
  const int bx = blockIdx.x;                 // t-group (64 t)
  const int d0 = blockIdx.y * 64;
  const int b = blockIdx.z;
  const int t0 = bx * 64;
  const int tid = threadIdx.x;
#pragma unroll
  for (int j = 0; j < 4; ++j) {
    const int chunk = tid + j * 256;
    const int r = chunk >> 4, c4 = (chunk & 15) * 4;
    const float4 v = *(const float4*)(H + ((size_t)(b * DIM + d0 + r)) * T_DIM + t0 + c4);
    *(float4*)(&tile[r * 68 + c4]) = v;
  }
  __syncthreads();
#pragma unroll
  for (int j = 0; j < 2; ++j) {
    const int chunk = tid + j * 256;
    const int q = chunk >> 3, e8 = (chunk & 7) * 8;   // t-local q, d-local group e8
    union { u16 us[8]; uint4 v4; } hi, lo;
#pragma unroll
    for (int k = 0; k < 8; ++k) {
      const float f = tile[(e8 + k) * 68 + q];
      const u16 h = f32_to_bf16(f);
      hi.us[k] = h;
      lo.us[k] = f32_to_bf16(f - bf16_to_f32(h));
    }
    const int dg = d0 + e8;
    const int chunkB = (q >> 5) * 64 + ((dg >> 3) & 1) * 32 + (q & 31);
    const size_t o = ((((size_t)b * 32 + bx) * 32 + (dg >> 4)) * 128 + chunkB) * 8;
    *(uint4*)(BpH + o) = hi.v4;
    *(uint4*)(BpL + o) = lo.v4;
  }
}

// ---------------- K1: fused register GEMM (32x32x16) + softmax ----------------
__global__ __launch_bounds__(512, 1) void k_fused(const u16* __restrict__ UpH, const u16* __restrict__ UpL,
                                                  const u16* __restrict__ BpH, const u16* __restrict__ BpL,
                                                  const float* __restrict__ msq,
                                                  float* __restrict__ out) {
  __shared__ float redM[8][128];
  __shared__ float redS[8][128];
  const int tid = threadIdx.x;
  const int lane = tid & 63, wv = tid >> 6;
  const int l31 = lane & 31, lhi = lane >> 5;
  const int sw = wv;                 // wave owns s rows [sw*128, +128) = tiles sw*4..+3

  const int tgx = blockIdx.x;        // 128-t group
  const int t00 = tgx * 128;
  const int bb = blockIdx.y;

  // ---- direct-from-global fragment bases (all loads: base + ks*stride + imm) ----
  const char* const aH = (const char*)UpH + (sw * 4) * 1024 + lane * 16;   // + ks*32768 + mt*1024
  const char* const aL = (const char*)UpL + (sw * 4) * 1024 + lane * 16;
  const size_t bg0 = (((size_t)bb * 32 + 2 * tgx) * 32) * 2048 + lane * 16;      // t-group 2*tgx
  const size_t bg1 = (((size_t)bb * 32 + 2 * tgx + 1) * 32) * 2048 + lane * 16;  // t-group 2*tgx+1
  const char* const bH0 = (const char*)BpH + bg0;   // + ks*2048 + nt*1024 (nt=0,1)
  const char* const bH1 = (const char*)BpH + bg1;   // (nt=2,3)
  const char* const bL0 = (const char*)BpL + bg0;
  const char* const bL1 = (const char*)BpL + bg1;

  f32x16 acc[4][4];
#pragma unroll
  for (int mt = 0; mt < 4; ++mt)
#pragma unroll
    for (int nt = 0; nt < 4; ++nt)
#pragma unroll
      for (int r = 0; r < 16; ++r)
        acc[mt][nt][r] = 0.f;

  short8 ah0[4], al0[4], bh0[4], bl0[4];
  short8 ah1[4], al1[4], bh1[4], bl1[4];

#define LOADSET(AH, AL, BH, BL, KS) do {                                  \
    const size_t koA = (size_t)(KS) * 32768;                              \
    const size_t koB = (size_t)(KS) * 2048;                               \
    _Pragma("unroll") for (int mt = 0; mt < 4; ++mt) {                    \
      (AH)[mt] = *(const short8*)(aH + koA + mt * 1024);                  \
      (AL)[mt] = *(const short8*)(aL + koA + mt * 1024);                  \
    }                                                                     \
    (BH)[0] = *(const short8*)(bH0 + koB);                                \
    (BH)[1] = *(const short8*)(bH0 + koB + 1024);                         \
    (BH)[2] = *(const short8*)(bH1 + koB);                                \
    (BH)[3] = *(const short8*)(bH1 + koB + 1024);                         \
    (BL)[0] = *(const short8*)(bL0 + koB);                                \
    (BL)[1] = *(const short8*)(bL0 + koB + 1024);                         \
    (BL)[2] = *(const short8*)(bL1 + koB);                                \
    (BL)[3] = *(const short8*)(bL1 + koB + 1024);                         \
  } while (0)

#define COMPUTE(AH, AL, BH, BL) do {                                      \
    __builtin_amdgcn_s_setprio(1);                                        \
    _Pragma("unroll") for (int mt = 0; mt < 4; ++mt)                      \
      _Pragma("unroll") for (int nt = 0; nt < 4; ++nt)                    \
        acc[mt][nt] = __builtin_amdgcn_mfma_f32_32x32x16_bf16((AH)[mt], (BH)[nt], acc[mt][nt], 0, 0, 0); \
    _Pragma("unroll") for (int mt = 0; mt < 4; ++mt)                      \
      _Pragma("unroll") for (int nt = 0; nt < 4; ++nt)                    \
        acc[mt][nt] = __builtin_amdgcn_mfma_f32_32x32x16_bf16((AH)[mt], (BL)[nt], acc[mt][nt], 0, 0, 0); \
    _Pragma("unroll") for (int mt = 0; mt < 4; ++mt)                      \
      _Pragma("unroll") for (int nt = 0; nt < 4; ++nt)                    \
        acc[mt][nt] = __builtin_amdgcn_mfma_f32_32x32x16_bf16((AL)[mt], (BH)[nt], acc[mt][nt], 0, 0, 0); \
    __builtin_amdgcn_s_setprio(0);                                        \
  } while (0)

  LOADSET(ah0, al0, bh0, bl0, 0);
#pragma unroll 1
  for (int k = 0; k < 32; k += 2) {
    LOADSET(ah1, al1, bh1, bl1, k + 1);
    COMPUTE(ah0, al0, bh0, bl0);
    const int k2 = (k + 2 < 32) ? (k + 2) : 31;   // tail: redundant load, never computed
    LOADSET(ah0, al0, bh0, bl0, k2);
    COMPUTE(ah1, al1, bh1, bl1);
  }

  // ---- epilogue: softmax over s, in registers (R6-verified C/D mapping) ----
  // s = sw*128 + mt*32 + lhi*4 + q*8 + r (reg=q*4+r); t = t00 + nt*32 + l31.
  float mx[4] = {-3.0e38f, -3.0e38f, -3.0e38f, -3.0e38f};
#pragma unroll
  for (int mt = 0; mt < 4; ++mt) {
    const int sb = sw * 128 + mt * 32 + lhi * 4;
#pragma unroll
    for (int q = 0; q < 4; ++q) {
      const f32x4 mq = *(const f32x4*)(msq + sb + q * 8);
#pragma unroll
      for (int nt = 0; nt < 4; ++nt)
#pragma unroll
        for (int r = 0; r < 4; ++r) {
          const int reg = q * 4 + r;
          const float v = 2.f * acc[mt][nt][reg] - mq[r];
          acc[mt][nt][reg] = v;
          mx[nt] = fmaxf(mx[nt], v);
        }
    }
  }
#pragma unroll
  for (int nt = 0; nt < 4; ++nt) mx[nt] = fmaxf(mx[nt], __shfl_xor(mx[nt], 32));
  if (lane < 32) {
#pragma unroll
    for (int nt = 0; nt < 4; ++nt) redM[wv][nt * 32 + l31] = mx[nt];
  }
  __syncthreads();
  float M[4];
#pragma unroll
  for (int nt = 0; nt < 4; ++nt) {
    float m = redM[0][nt * 32 + l31];
#pragma unroll
    for (int w = 1; w < 8; ++w) m = fmaxf(m, redM[w][nt * 32 + l31]);
    M[nt] = m;
  }
  float sum[4] = {0.f, 0.f, 0.f, 0.f};
#pragma unroll
  for (int mt = 0; mt < 4; ++mt)
#pragma unroll
    for (int nt = 0; nt < 4; ++nt)
#pragma unroll
      for (int reg = 0; reg < 16; ++reg) {
        const float e = __expf(acc[mt][nt][reg] - M[nt]);
        acc[mt][nt][reg] = e;
        sum[nt] += e;
      }
#pragma unroll
  for (int nt = 0; nt < 4; ++nt) sum[nt] += __shfl_xor(sum[nt], 32);
  if (lane < 32) {
#pragma unroll
    for (int nt = 0; nt < 4; ++nt) redS[wv][nt * 32 + l31] = sum[nt];
  }
  __syncthreads();
  float rs[4];
#pragma unroll
  for (int nt = 0; nt < 4; ++nt) {
    float s = redS[0][nt * 32 + l31];
#pragma unroll
    for (int w = 1; w < 8; ++w) s += redS[w][nt * 32 + l31];
    rs[nt] = 1.0f / s;
  }

  float* const outb = out + ((size_t)bb << 21);   // b * 1024 * 2048
#pragma unroll
  for (int mt = 0; mt < 4; ++mt) {
    const int sb = sw * 128 + mt * 32 + lhi * 4;
#pragma unroll
    for (int q = 0; q < 4; ++q)
#pragma unroll
      for (int r = 0; r < 4; ++r) {
        const int srow = sb + q * 8 + r;
        const int reg = q * 4 + r;
        float* const orow = outb + (size_t)srow * T_DIM + t00 + l31;
#pragma unroll
        for (int nt = 0; nt < 4; ++nt)
          orow[nt * 32] = acc[mt][nt][reg] * rs[nt];
      }
  }
}

// ---------------- launch ----------------
extern "C" void kernel_launch(void* const* d_in, const int* in_sizes, int n_in,
                              void* d_out, int out_size, void* d_ws, size_t ws_size,
                              hipStream_t stream) {
  (void)in_sizes; (void)n_in; (void)out_size; (void)ws_size;
  const float* H = (const float*)d_in[0];
  const float* units = (const float*)d_in[1];
  float* out = (float*)d_out;
  char* ws = (char*)d_ws;
  u16* BpH = (u16*)(ws);
  u16* BpL = (u16*)(ws + 134217728);
  u16* UpH = (u16*)(ws + 268435456);
  u16* UpL = (u16*)(ws + 269484032);
  float* msq = (float*)(ws + 270532608);

  k_prep_units<<<dim3(S_DIM / 4), 256, 0, stream>>>(units, UpH, UpL, msq);
  k_prep_h<<<dim3(T_DIM / 64, DIM / 64, B_DIM), 256, 0, stream>>>(H, BpH, BpL);
  k_fused<<<dim3(T_DIM / 128, B_DIM), 512, 0, stream>>>(UpH, UpL, BpH, BpL, msq, out);
}

// Round 8
// 572.311 us; speedup vs baseline: 11.6020x; 11.6020x over previous
//
#include <hip/hip_runtime.h>
#include <stdint.h>

// Problem: B=64, DIM=512, T=2048, S=1024.
// out[b][s][t] = softmax_s( 2*cross - msq[s] ),  cross = sum_d units[d][s]*H[b][d][t].
// Pipeline:
//   k_prep_units: units fp32 -> Upack hi/lo (MFMA-fragment-slab order) + msq[s].
//   k_prep_h:     H fp32 -> Bpack hi/lo (fragment-slab order per (b, t-group-64)).
//   k_fused:      FULL-S GEMM (1024s x 64t per block; wave tile 128s x 64t) via
//                 mfma_f32_32x32x16_bf16, 3-term hi/lo. NO LDS / NO barriers in
//                 K-loop: fragment-packed operands load straight global->VGPR.
//                 Register budget sized to the 256-reg/wave cap (512-thr block =
//                 2 waves/SIMD): acc 128 + ah dbuf 32 + bh dbuf 16 + al 16 + bl 8.
//                 In-register softmax epilogue (4KB LDS reductions only).
// ws: BpackH[0,128M) BpackL[128M,256M) UpackH(1M) UpackL(1M) msq(4K) => ~258 MB.

typedef unsigned short u16;
typedef __attribute__((ext_vector_type(8))) short short8;    // 8 x bf16 (4 VGPR)
typedef __attribute__((ext_vector_type(4))) float f32x4;
typedef __attribute__((ext_vector_type(16))) float f32x16;   // 32x32 C/D

#define B_DIM 64
#define DIM   512
#define T_DIM 2048
#define S_DIM 1024

__device__ __forceinline__ u16 f32_to_bf16(float f) {
  uint32_t u = __float_as_uint(f);
  uint32_t r = u + 0x7FFFu + ((u >> 16) & 1u);   // RNE
  return (u16)(r >> 16);
}
__device__ __forceinline__ float bf16_to_f32(u16 h) {
  return __uint_as_float(((uint32_t)h) << 16);
}

// ---------------- K0a: units -> Upack hi/lo + msq ----------------
__global__ __launch_bounds__(256) void k_prep_units(const float* __restrict__ units,
                                                    u16* __restrict__ UpH, u16* __restrict__ UpL,
                                                    float* __restrict__ msq) {
  const int s0 = blockIdx.x * 4;
  const int tid = threadIdx.x;
  const int lane = tid & 63, wv = tid >> 6;
  float acc0 = 0.f, acc1 = 0.f, acc2 = 0.f, acc3 = 0.f;
#pragma unroll
  for (int j = 0; j < 2; ++j) {
    const int d = tid + j * 256;
    const float4 v = *(const float4*)(units + (size_t)d * S_DIM + s0);
    acc0 += v.x * v.x; acc1 += v.y * v.y; acc2 += v.z * v.z; acc3 += v.w * v.w;
    const int dbase = (d >> 4) * 16384 + ((d >> 3) & 1) * 256 + (d & 7);
    const float fv[4] = {v.x, v.y, v.z, v.w};
#pragma unroll
    for (int q = 0; q < 4; ++q) {
      const int s = s0 + q;
      const int idx = dbase + ((s >> 5) * 64 + (s & 31)) * 8;
      const u16 h = f32_to_bf16(fv[q]);
      UpH[idx] = h;
      UpL[idx] = f32_to_bf16(fv[q] - bf16_to_f32(h));
    }
  }
#pragma unroll
  for (int off = 1; off < 64; off <<= 1) {
    acc0 += __shfl_xor(acc0, off);
    acc1 += __shfl_xor(acc1, off);
    acc2 += __shfl_xor(acc2, off);
    acc3 += __shfl_xor(acc3, off);
  }
  __shared__ float part[4][4];
  if (lane == 0) { part[wv][0] = acc0; part[wv][1] = acc1; part[wv][2] = acc2; part[wv][3] = acc3; }
  __syncthreads();
  if (tid < 4) msq[s0 + tid] = part[0][tid] + part[1][tid] + part[2][tid] + part[3][tid];
}

// ---------------- K0b: H [b][d][t] -> Bpack hi/lo ----------------
__global__ __launch_bounds__(256) void k_prep_h(const float* __restrict__ H,
                                                u16* __restrict__ BpH, u16* __restrict__ BpL) {
  __shared__ float tile[64 * 68];
  const int bx = blockIdx.x;                 // t-group (64 t)
  const int d0 = blockIdx.y * 64;
  const int b = blockIdx.z;
  const int t0 = bx * 64;
  const int tid = threadIdx.x;
#pragma unroll
  for (int j = 0; j < 4; ++j) {
    const int chunk = tid + j * 256;
    const int r = chunk >> 4, c4 = (chunk & 15) * 4;
    const float4 v = *(const float4*)(H + ((size_t)(b * DIM + d0 + r)) * T_DIM + t0 + c4);
    *(float4*)(&tile[r * 68 + c4]) = v;
  }
  __syncthreads();
#pragma unroll
  for (int j = 0; j < 2; ++j) {
    const int chunk = tid + j * 256;
    const int q = chunk >> 3, e8 = (chunk & 7) * 8;   // t-local q, d-local group e8
    union { u16 us[8]; uint4 v4; } hi, lo;
#pragma unroll
    for (int k = 0; k < 8; ++k) {
      const float f = tile[(e8 + k) * 68 + q];
      const u16 h = f32_to_bf16(f);
      hi.us[k] = h;
      lo.us[k] = f32_to_bf16(f - bf16_to_f32(h));
    }
    const int dg = d0 + e8;
    const int chunkB = (q >> 5) * 64 + ((dg >> 3) & 1) * 32 + (q & 31);
    const size_t o = ((((size_t)b * 32 + bx) * 32 + (dg >> 4)) * 128 + chunkB) * 8;
    *(uint4*)(BpH + o) = hi.v4;
    *(uint4*)(BpL + o) = lo.v4;
  }
}

// ---------------- K1: fused register GEMM (32x32x16) + softmax ----------------
__global__ __launch_bounds__(512, 2) void k_fused(const u16* __restrict__ UpH, const u16* __restrict__ UpL,
                                                  const u16* __restrict__ BpH, const u16* __restrict__ BpL,
                                                  const float* __restrict__ msq,
                                                  float* __restrict__ out) {
  __shared__ float redM[8][64];
  __shared__ float redS[8][64];
  const int tid = threadIdx.x;
  const int lane = tid & 63, wv = tid >> 6;
  const int l31 = lane & 31, lhi = lane >> 5;
  const int sw = wv;                 // wave owns s rows [sw*128, +128) = tiles sw*4..+3

  const int tgx = blockIdx.x;        // 64-t group
  const int t00 = tgx * 64;
  const int bb = blockIdx.y;

  // ---- direct-from-global fragment bases (R7-verified layouts) ----
  const char* const aH = (const char*)UpH + (sw * 4) * 1024 + lane * 16;   // + ks*32768 + mt*1024
  const char* const aL = (const char*)UpL + (sw * 4) * 1024 + lane * 16;
  const size_t bg = (((size_t)bb * 32 + tgx) * 32) * 2048 + lane * 16;     // + ks*2048 + nt*1024
  const char* const bH = (const char*)BpH + bg;
  const char* const bL = (const char*)BpL + bg;

  f32x16 acc[4][2];
#pragma unroll
  for (int mt = 0; mt < 4; ++mt)
#pragma unroll
    for (int nt = 0; nt < 2; ++nt)
#pragma unroll
      for (int r = 0; r < 16; ++r)
        acc[mt][nt][r] = 0.f;

  short8 ahA[4], ahB[4];   // dbuf (even/odd slab)
  short8 bhA[2], bhB[2];   // dbuf
  short8 al[4];            // single-buffer
  short8 bl[2];            // single-buffer

#define LD_AH(D, KS) do { const size_t ko = (size_t)(KS) * 32768;            \
    (D)[0] = *(const short8*)(aH + ko);                                      \
    (D)[1] = *(const short8*)(aH + ko + 1024);                               \
    (D)[2] = *(const short8*)(aH + ko + 2048);                               \
    (D)[3] = *(const short8*)(aH + ko + 3072); } while (0)
#define LD_AL(D, KS) do { const size_t ko = (size_t)(KS) * 32768;            \
    (D)[0] = *(const short8*)(aL + ko);                                      \
    (D)[1] = *(const short8*)(aL + ko + 1024);                               \
    (D)[2] = *(const short8*)(aL + ko + 2048);                               \
    (D)[3] = *(const short8*)(aL + ko + 3072); } while (0)
#define LD_BH(D, KS) do { const size_t ko = (size_t)(KS) * 2048;             \
    (D)[0] = *(const short8*)(bH + ko);                                      \
    (D)[1] = *(const short8*)(bH + ko + 1024); } while (0)
#define LD_BL(D, KS) do { const size_t ko = (size_t)(KS) * 2048;             \
    (D)[0] = *(const short8*)(bL + ko);                                      \
    (D)[1] = *(const short8*)(bL + ko + 1024); } while (0)

#define MM8(AF, BF)                                                          \
    __builtin_amdgcn_s_setprio(1);                                           \
    _Pragma("unroll") for (int mt = 0; mt < 4; ++mt)                         \
      _Pragma("unroll") for (int nt = 0; nt < 2; ++nt)                       \
        acc[mt][nt] = __builtin_amdgcn_mfma_f32_32x32x16_bf16((AF)[mt], (BF)[nt], acc[mt][nt], 0, 0, 0); \
    __builtin_amdgcn_s_setprio(0);

  // ---- prologue ----
  LD_AH(ahA, 0); LD_BH(bhA, 0); LD_BL(bl, 0); LD_AL(al, 0);
  LD_AH(ahB, 1); LD_BH(bhB, 1);

#pragma unroll 1
  for (int k = 0; k < 32; k += 2) {
    const int kc2 = (k + 2 < 32) ? (k + 2) : 30;   // clamped redundant tail loads
    const int kc3 = (k + 3 < 32) ? (k + 3) : 31;
    // ---- slab k (even): ahA, bhA, al, bl ----
    MM8(ahA, bhA);                       // P1
    MM8(ahA, bl);                        // P2 (ahA, bl dead after issue)
    LD_BL(bl, k + 1);                    // cover: P3 + P1(k+1)
    LD_AH(ahA, kc2);                     // cover: ~2 slabs
    MM8(al, bhA);                        // P3 (al, bhA dead)
    LD_AL(al, k + 1);                    // cover: P1+P2 of k+1
    LD_BH(bhA, kc2);
    // ---- slab k+1 (odd): ahB, bhB, al, bl ----
    MM8(ahB, bhB);
    MM8(ahB, bl);
    LD_BL(bl, kc2);
    LD_AH(ahB, kc3);
    MM8(al, bhB);
    LD_AL(al, kc2);
    LD_BH(bhB, kc3);
  }

  // ---- epilogue: softmax over s, in registers (R6-verified C/D mapping) ----
  // s = sw*128 + mt*32 + lhi*4 + q*8 + r (reg=q*4+r); t = t00 + nt*32 + l31.
  float mx0 = -3.0e38f, mx1 = -3.0e38f;
#pragma unroll
  for (int mt = 0; mt < 4; ++mt) {
    const int sb = sw * 128 + mt * 32 + lhi * 4;
#pragma unroll
    for (int q = 0; q < 4; ++q) {
      const f32x4 mq = *(const f32x4*)(msq + sb + q * 8);
#pragma unroll
      for (int r = 0; r < 4; ++r) {
        const int reg = q * 4 + r;
        const float v0 = 2.f * acc[mt][0][reg] - mq[r];
        const float v1 = 2.f * acc[mt][1][reg] - mq[r];
        acc[mt][0][reg] = v0; acc[mt][1][reg] = v1;
        mx0 = fmaxf(mx0, v0); mx1 = fmaxf(mx1, v1);
      }
    }
  }
  mx0 = fmaxf(mx0, __shfl_xor(mx0, 32));
  mx1 = fmaxf(mx1, __shfl_xor(mx1, 32));
  if (lane < 32) { redM[wv][l31] = mx0; redM[wv][32 + l31] = mx1; }
  __syncthreads();
  float M0 = redM[0][l31], M1 = redM[0][32 + l31];
#pragma unroll
  for (int w = 1; w < 8; ++w) {
    M0 = fmaxf(M0, redM[w][l31]);
    M1 = fmaxf(M1, redM[w][32 + l31]);
  }
  float s0 = 0.f, s1 = 0.f;
#pragma unroll
  for (int mt = 0; mt < 4; ++mt)
#pragma unroll
    for (int reg = 0; reg < 16; ++reg) {
      const float e0 = __expf(acc[mt][0][reg] - M0);
      const float e1 = __expf(acc[mt][1][reg] - M1);
      acc[mt][0][reg] = e0; acc[mt][1][reg] = e1;
      s0 += e0; s1 += e1;
    }
  s0 += __shfl_xor(s0, 32);
  s1 += __shfl_xor(s1, 32);
  if (lane < 32) { redS[wv][l31] = s0; redS[wv][32 + l31] = s1; }
  __syncthreads();
  float S0 = redS[0][l31], S1 = redS[0][32 + l31];
#pragma unroll
  for (int w = 1; w < 8; ++w) {
    S0 += redS[w][l31];
    S1 += redS[w][32 + l31];
  }
  const float r0 = 1.0f / S0, r1 = 1.0f / S1;

  float* const outb = out + ((size_t)bb << 21);   // b * 1024 * 2048
  const int tc0 = t00 + l31, tc1 = t00 + 32 + l31;
#pragma unroll
  for (int mt = 0; mt < 4; ++mt) {
    const int sb = sw * 128 + mt * 32 + lhi * 4;
#pragma unroll
    for (int q = 0; q < 4; ++q)
#pragma unroll
      for (int r = 0; r < 4; ++r) {
        const int srow = sb + q * 8 + r;
        const int reg = q * 4 + r;
        outb[(size_t)srow * T_DIM + tc0] = acc[mt][0][reg] * r0;
        outb[(size_t)srow * T_DIM + tc1] = acc[mt][1][reg] * r1;
      }
  }
}

// ---------------- launch ----------------
extern "C" void kernel_launch(void* const* d_in, const int* in_sizes, int n_in,
                              void* d_out, int out_size, void* d_ws, size_t ws_size,
                              hipStream_t stream) {
  (void)in_sizes; (void)n_in; (void)out_size; (void)ws_size;
  const float* H = (const float*)d_in[0];
  const float* units = (const float*)d_in[1];
  float* out = (float*)d_out;
  char* ws = (char*)d_ws;
  u16* BpH = (u16*)(ws);
  u16* BpL = (u16*)(ws + 134217728);
  u16* UpH = (u16*)(ws + 268435456);
  u16* UpL = (u16*)(ws + 269484032);
  float* msq = (float*)(ws + 270532608);

  k_prep_units<<<dim3(S_DIM / 4), 256, 0, stream>>>(units, UpH, UpL, msq);
  k_prep_h<<<dim3(T_DIM / 64, DIM / 64, B_DIM), 256, 0, stream>>>(H, BpH, BpL);
  k_fused<<<dim3(T_DIM / 64, B_DIM), 512, 0, stream>>>(UpH, UpL, BpH, BpL, msq, out);
}